// Round 5
// baseline (148.368 us; speedup 1.0000x reference)
//
#include <hip/hip_runtime.h>
#include <stdint.h>

#define HH 224
#define WW 224
#define BB 4
#define PP 7          // seams per direction
#define SEG 28
#define BW 5
#define MM 11         // 2*BW+1

#define POS_INF_I 0x7F800000

typedef const __attribute__((address_space(1))) unsigned int* gas_ptr;
typedef __attribute__((address_space(3))) unsigned int* las_ptr;
typedef unsigned long long ull;

__device__ __forceinline__ int iclamp(int v, int lo, int hi) {
    return min(max(v, lo), hi);
}

// map-compose for 11-entry 4-bit-nibble maps packed in u64:  H[i] = F[G[i]]
__device__ inline ull mcompose(ull F, ull G) {
    ull H = 0ull;
#pragma unroll
    for (int i = 0; i < 11; ++i) {
        unsigned g = (unsigned)(G >> (4 * i)) & 15u;
        H |= ((F >> (4 * g)) & 15ull) << (4 * i);
    }
    return H;
}

// ---------------------------------------------------------------------------
// DP kernel (verified absmax 0 — unchanged)
// ---------------------------------------------------------------------------
__global__ __launch_bounds__(64) void dp_kernel(const float* __restrict__ grad,
                                                int* __restrict__ coords_v,
                                                int* __restrict__ coords_h) {
    __shared__ __align__(16) float gseg[225 * 16];

    const int tid = threadIdx.x;
    const int l   = tid & 15;
    const int sid = blockIdx.x;
    const int p   = sid % PP;
    const int dir = (sid / PP) & 1;
    const int b   = sid / (2 * PP);
    const int base = SEG * (p + 1);
    const float* gb = grad + b * (HH * WW);

    {
        const int r  = tid >> 4;
        const int m  = tid & 15;
        const int sS = (dir == 0) ? WW : 1;
        const int sM = (dir == 0) ? 1  : WW;
        const float* src = gb + r * sS + (base - BW + m) * sM;
        const long stepBytes = (long)(4 * sS) * 4;
#pragma unroll 8
        for (int c = 0; c < 56; ++c) {
            __builtin_amdgcn_global_load_lds((gas_ptr)(const void*)src,
                                             (las_ptr)(void*)(&gseg[c * 64]), 4, 0, 0);
            src = (const float*)((const char*)src + stepBytes);
        }
    }
    __syncthreads();

    const float lane_add = (l < MM) ? 0.0f : __int_as_float(POS_INF_I);
    const float* gp = &gseg[l];

    unsigned wreg[16] = {};

#define DP_STEP(gval, ownb, jj_c)                                                       \
    {                                                                                   \
        float v1 = cost;                                                                \
        float v0 = __int_as_float(__builtin_amdgcn_update_dpp(                          \
            POS_INF_I, __float_as_int(cost), 0x111, 0xf, 0xf, false));                  \
        float v2 = __int_as_float(__builtin_amdgcn_update_dpp(                          \
            POS_INF_I, __float_as_int(cost), 0x101, 0xf, 0xf, false));                  \
        bool a01 = (v0 <= v1), a02 = (v0 <= v2), a12 = (v1 <= v2);                      \
        bool aa  = a01 && a02;                                                          \
        unsigned long long A   = __ballot(aa);                                          \
        unsigned long long C12 = __ballot(a12);                                         \
        unsigned long long B0 = ~A & C12;                                               \
        unsigned long long B1 = ~A & ~C12;                                              \
        float mv = aa ? v0 : (a12 ? v1 : v2);                                           \
        cost = mv - (gval) + lane_add;                                                  \
        unsigned wv = (unsigned)(B0 & 0x7FFull) | ((unsigned)(B1 & 0x7FFull) << 11);    \
        wreg[(jj_c)] = (ownb) ? wv : wreg[(jj_c)];                                      \
    }

    float cost = -gp[0] + lane_add;
    float buf[16], c0[16];
#pragma unroll
    for (int k = 0; k < 16; ++k) buf[k] = gp[(1 + k) * 16];
    for (int t = 0; t < 13; ++t) {
        const bool own = (tid == t);
#pragma unroll
        for (int k = 0; k < 16; ++k) c0[k] = buf[k];
#pragma unroll
        for (int k = 0; k < 16; ++k) buf[k] = gp[(16 * (t + 1) + 1 + k) * 16];
#pragma unroll
        for (int k = 0; k < 16; ++k) DP_STEP(c0[k], own, k)
    }
    {
        const bool own = (tid == 13);
#pragma unroll
        for (int k = 0; k < 15; ++k) DP_STEP(buf[k], own, k)
    }
#undef DP_STEP

    float bc = cost;
    int   bi = l;
#pragma unroll
    for (int mask = 1; mask < 16; mask <<= 1) {
        float oc = __shfl_xor(bc, mask, 16);
        int   oi = __shfl_xor(bi, mask, 16);
        if (oc < bc || (oc == bc && oi < bi)) { bc = oc; bi = oi; }
    }
    const int idx_last = bi;

    const int mcnt = (l < 13) ? 16 : ((l == 13) ? 15 : 0);
    const ull IDMAP = 0xA9876543210ull;
    ull L = IDMAP;
#pragma unroll
    for (int jj = 15; jj >= 0; --jj) {
        if (jj < mcnt) {
            unsigned ww = wreg[jj];
            ull M = 0ull;
#pragma unroll
            for (int i = 0; i < MM; ++i) {
                unsigned sel = ((ww >> i) & 1u) + 2u * ((ww >> (11 + i)) & 1u);
                M |= ((ull)(i + (int)sel - 1)) << (4 * i);
            }
            L = mcompose(M, L);
        }
    }
    ull I = L;
#pragma unroll
    for (int d = 1; d < 16; d <<= 1) {
        ull O = __shfl_down(I, d, 16);
        if (l + d < 16) I = mcompose(I, O);
    }
    ull R = __shfl_down(I, 1, 16);
    if (l == 15) R = IDMAP;

    int* cout = (dir == 0) ? coords_v : coords_h;
    if (tid == 15) cout[(b * HH + 223) * PP + p] = base + idx_last - BW;
    if (tid < 16) {
        unsigned v = (unsigned)(R >> (4 * idx_last)) & 15u;
#pragma unroll
        for (int jj = 15; jj >= 0; --jj) {
            if (jj < mcnt) {
                unsigned ww = wreg[jj];
                unsigned sel = ((ww >> v) & 1u) + 2u * ((ww >> (11 + v)) & 1u);
                v = v + sel - 1u;
                cout[(b * HH + (16 * l + jj)) * PP + p] = base + (int)v - BW;
            }
        }
    }
}

// ---------------------------------------------------------------------------
// Proven LDS-bins slow path (round-0 logic, verbatim) — the FALLBACK.
// (x,y) are the voting pixel's true (clamped) global coords.
// ---------------------------------------------------------------------------
__device__ __forceinline__ int slow_vote_bins(const ull* rows, int x, int y, int t,
                                              unsigned* __restrict__ bins) {
#pragma unroll
    for (int c = 0; c < 16; ++c) bins[c * 256 + t] = 0u;
#pragma unroll
    for (int dy = -3; dy <= 3; ++dy) {
        if ((unsigned)(y + dy) >= (unsigned)HH) continue;
        ull row = rows[dy + 3];
        const int ay = dy < 0 ? -dy : dy;
#pragma unroll
        for (int dx = -3; dx <= 3; ++dx) {
            if ((unsigned)(x + dx) >= (unsigned)WW) continue;
            int lb = (int)((row >> (8 * (dx + 3))) & 255u);
            const int ax = dx < 0 ? -dx : dx;
            const int d = ay > ax ? ay : ax;
            const unsigned wgt = (d <= 1) ? 3u : (unsigned)(4 - d);
            atomicAdd(&bins[(lb >> 2) * 256 + t], wgt << ((lb & 3) * 8));
        }
    }
    int best_s = 0, best_k = 0;
#pragma unroll
    for (int c = 0; c < 16; ++c) {
        unsigned wd = bins[c * 256 + t];
        if (wd) {
#pragma unroll
            for (int q = 0; q < 4; ++q) {
                int s = (int)((wd >> (q * 8)) & 255u);
                if (s > best_s) { best_s = s; best_k = c * 4 + q; }
            }
        }
    }
    return best_k;
}

// ---------------------------------------------------------------------------
// Register-only SWAR slow path (verified absmax 0 in rounds 3/4 — unchanged).
// ---------------------------------------------------------------------------
#define SW_K1   0x0001010101010101ull
#define SW_HI7  0x0080808080808080ull
#define SW_LO7  0x007F7F7F7F7F7F7Full
#define SW_W1   0x0001020303030201ull   /* rows |dy|<=1: [1,2,3,3,3,2,1] */
#define SW_W2   0x0001020202020201ull   /* rows |dy|==2: [1,2,2,2,2,2,1] */

__device__ __forceinline__ ull sw_zm(ull xv) {
    return (~(((xv & SW_LO7) + SW_LO7) | xv)) & SW_HI7;
}
__device__ __forceinline__ int sw_dotm(ull m, ull W) {
    return (int)((((m >> 7) * W) >> 48) & 0xFFull);
}

__device__ __forceinline__ int swar_or_bins(const ull* rows, int x, int y,
                                            unsigned cl, int t,
                                            unsigned* __restrict__ bins) {
    // x-validity: marker at byte dx iff 0 <= x+dx-3 < WW
    ull vmx = SW_HI7;
    if (x < 3)   vmx &= (~0ull) << (8 * (3 - x));
    if (x > 220) vmx &= (1ull << (8 * (227 - x))) - 1ull;

    unsigned c1 = 254u, c2 = 254u, c3 = 254u;   // 254 = empty slot (never a label)
    int s0 = 0, s1 = 0, s2 = 0, s3 = 0;
    bool ovf = false;
    const ull rep0 = (ull)cl * SW_K1;

#pragma unroll
    for (int r = 0; r < 7; ++r) {
        if ((unsigned)(y + r - 3) >= (unsigned)HH) continue;
        const ull row = rows[r];
        const int ay   = r < 3 ? 3 - r : r - 3;        // compile-time per r
        const bool POPC = (ay == 3);                    // weight row all-ones
        const ull W    = (ay <= 1) ? SW_W1 : SW_W2;

        ull e0 = sw_zm(row ^ rep0) & vmx;
        ull e1 = sw_zm(row ^ ((ull)c1 * SW_K1)) & vmx;
        ull e2 = sw_zm(row ^ ((ull)c2 * SW_K1)) & vmx;
        ull e3 = sw_zm(row ^ ((ull)c3 * SW_K1)) & vmx;
        s0 += POPC ? __popcll(e0) : sw_dotm(e0, W);
        s1 += POPC ? __popcll(e1) : sw_dotm(e1, W);
        s2 += POPC ? __popcll(e2) : sw_dotm(e2, W);
        s3 += POPC ? __popcll(e3) : sw_dotm(e3, W);

        ull rem = vmx & ~(e0 | e1 | e2 | e3);
        for (int it = 0; it < 3 && rem; ++it) {
            int pos = (int)__builtin_ctzll(rem);        // marker bit = 8k+7
            unsigned nb = (unsigned)((row >> (pos - 7)) & 255u);
            ull en = sw_zm(row ^ ((ull)nb * SW_K1)) & vmx;
            int dn = POPC ? __popcll(en) : sw_dotm(en, W);
            if      (c1 == 254u) { c1 = nb; s1 += dn; }
            else if (c2 == 254u) { c2 = nb; s2 += dn; }
            else if (c3 == 254u) { c3 = nb; s3 += dn; }
            else ovf = true;
            rem &= ~en;
        }
        if (rem) ovf = true;
    }

    if (ovf) return slow_vote_bins(rows, x, y, t, bins);

    int bs = s0; unsigned bl = cl;
    if (s1 > bs || (s1 == bs && c1 < bl)) { bs = s1; bl = c1; }
    if (s2 > bs || (s2 == bs && c2 < bl)) { bs = s2; bl = c2; }
    if (s3 > bs || (s3 == bs && c3 < bl)) { bs = s3; bl = c3; }
    return (int)bl;
}

// ---------------------------------------------------------------------------
// 7x7-window gather from an LDS label region of row stride STR: rows
// cy0..cy0+6, cols cx0..cx0+6, one packed 56-bit row per ull. Unaligned 8B
// read = two aligned b64 + funnel shift. Callers guarantee
// (cy0+6)*STR + cx0 rounded down to 8 plus 16 bytes stays within the buffer.
// ---------------------------------------------------------------------------
template<int STR>
__device__ __forceinline__ void gather7(const unsigned char* lab,
                                        int cx0, int cy0, ull* rows) {
#pragma unroll
    for (int r = 0; r < 7; ++r) {
        int o  = (cy0 + r) * STR + cx0;
        int a8 = o & ~7;
        int sh = (o & 7) * 8;
        ull lo = *reinterpret_cast<const ull*>(lab + a8);
        ull hi = *reinterpret_cast<const ull*>(lab + a8 + 8);
        ull row = lo >> sh;
        if (sh) row |= hi << (64 - sh);
        rows[r] = row & 0x00FFFFFFFFFFFFFFull;
    }
}

// one vote: uniform fast path (exact: all clamped bytes == center => center
// is the unique positive vote) else SWAR else bins. (x,y) = clamped coords.
__device__ __forceinline__ int do_vote(const ull* rows, int x, int y, int t,
                                       unsigned* __restrict__ bins) {
    const unsigned cl = (unsigned)((rows[3] >> 24) & 255u);
    const ull rep = (ull)cl * SW_K1;
    bool uni = true;
#pragma unroll
    for (int k = 0; k < 7; ++k) uni = uni && (rows[k] == rep);
    if (uni) return (int)cl;
    return swar_or_bins(rows, x, y, cl, t, bins);
}

// ---------------------------------------------------------------------------
// K1: analytic labels over clamped 44x20 region -> v1 over 38x14 -> v2 over
// the 32x8 tile -> out8. Region semantics: index k <-> clamped global coord,
// so edge-duplicated entries are consistent (proven round-4 pattern).
// Grid (7,28,4) x (32,8). LDS = 560+1232+960+560+16384 = 19696 B.
// ---------------------------------------------------------------------------
__global__ __launch_bounds__(256) void labvote2_kernel(const int* __restrict__ cv,
                                                       const int* __restrict__ ch,
                                                       unsigned char* __restrict__ out8) {
    __shared__ int cvs[20 * PP];                      // rows GY0-6..GY0+13 (clamped)
    __shared__ int chs[44 * PP];                      // cols GX0-6..GX0+37 (clamped)
    __shared__ __align__(8) unsigned char labR[20 * 48];   // init labels, 44x20
    __shared__ __align__(8) unsigned char labS[14 * 40];   // v1 out, 38x14
    __shared__ unsigned bins[16 * 256];

    const int tx = threadIdx.x, ty = threadIdx.y;
    const int t  = ty * 32 + tx;
    const int b  = blockIdx.z;
    const int GX0 = blockIdx.x * 32, GY0 = blockIdx.y * 8;

    // stage seam-coord slices
    for (int idx = t; idx < 20 * PP; idx += 256) {
        int gyc = iclamp(GY0 - 6 + idx / PP, 0, HH - 1);
        cvs[idx] = cv[(b * HH + gyc) * PP + idx % PP];
    }
    for (int idx = t; idx < 44 * PP; idx += 256) {
        int gxc = iclamp(GX0 - 6 + idx / PP, 0, WW - 1);
        chs[idx] = ch[(b * WW + gxc) * PP + idx % PP];
    }
    __syncthreads();

    // initial labels over clamped 44x20
    for (int idx = t; idx < 44 * 20; idx += 256) {
        int j = idx / 44, i = idx - j * 44;
        int gxc = iclamp(GX0 - 6 + i, 0, WW - 1);
        int gyc = iclamp(GY0 - 6 + j, 0, HH - 1);
        int v = 0, h = 0;
#pragma unroll
        for (int q = 0; q < PP; ++q) {
            v += (cvs[j * PP + q] <= gxc);
            h += (chs[i * PP + q] <= gyc);
        }
        labR[j * 48 + i] = (unsigned char)(v + 8 * h);
    }
    __syncthreads();

    // v1 over 38x14 (voting pixel = clamp(GX0-3+i, GY0-3+j))
    for (int idx = t; idx < 38 * 14; idx += 256) {
        int j = idx / 38, i = idx - j * 38;
        int gxc = iclamp(GX0 - 3 + i, 0, WW - 1);
        int gyc = iclamp(GY0 - 3 + j, 0, HH - 1);
        int cx0 = gxc - GX0 + 3;                      // window origin in labR
        int cy0 = gyc - GY0 + 3;
        ull rows[7];
        gather7<48>(labR, cx0, cy0, rows);
        labS[j * 40 + i] = (unsigned char)do_vote(rows, gxc, gyc, t, bins);
    }
    __syncthreads();

    // v2 for the 32x8 tile, one pixel per thread
    {
        const int x = GX0 + tx, y = GY0 + ty;
        ull rows[7];
        gather7<40>(labS, tx, ty, rows);
        out8[(b * HH + y) * WW + x] = (unsigned char)do_vote(rows, x, y, t, bins);
    }
}

// ---------------------------------------------------------------------------
// K2: stage v2 image over clamped 50x26 -> v3 (44x20) -> v4 (38x14) ->
// v5 (32x8) -> int32 out. Grid (7,28,4) x (32,8).
// LDS = 1456+960+560+16384 = 19360 B.
// ---------------------------------------------------------------------------
__global__ __launch_bounds__(256) void vote3_kernel(const unsigned char* __restrict__ in,
                                                    int* __restrict__ out32) {
    __shared__ __align__(8) unsigned char labA[26 * 56];   // v2 staged, 50x26
    __shared__ __align__(8) unsigned char labB[20 * 48];   // v3 out, 44x20
    __shared__ __align__(8) unsigned char labC[14 * 40];   // v4 out, 38x14
    __shared__ unsigned bins[16 * 256];

    const int tx = threadIdx.x, ty = threadIdx.y;
    const int t  = ty * 32 + tx;
    const int b  = blockIdx.z;
    const int GX0 = blockIdx.x * 32, GY0 = blockIdx.y * 8;
    const unsigned char* img = in + b * (HH * WW);

    // stage clamped 50x26 region of the v2 label image
    for (int idx = t; idx < 50 * 26; idx += 256) {
        int j = idx / 50, i = idx - j * 50;
        int gxc = iclamp(GX0 - 9 + i, 0, WW - 1);
        int gyc = iclamp(GY0 - 9 + j, 0, HH - 1);
        labA[j * 56 + i] = img[gyc * WW + gxc];
    }
    __syncthreads();

    // v3 over 44x20
    for (int idx = t; idx < 44 * 20; idx += 256) {
        int j = idx / 44, i = idx - j * 44;
        int gxc = iclamp(GX0 - 6 + i, 0, WW - 1);
        int gyc = iclamp(GY0 - 6 + j, 0, HH - 1);
        int cx0 = gxc - GX0 + 6;                      // origin in labA (o=GX0-9, +9-3)
        int cy0 = gyc - GY0 + 6;
        ull rows[7];
        gather7<56>(labA, cx0, cy0, rows);
        labB[j * 48 + i] = (unsigned char)do_vote(rows, gxc, gyc, t, bins);
    }
    __syncthreads();

    // v4 over 38x14
    for (int idx = t; idx < 38 * 14; idx += 256) {
        int j = idx / 38, i = idx - j * 38;
        int gxc = iclamp(GX0 - 3 + i, 0, WW - 1);
        int gyc = iclamp(GY0 - 3 + j, 0, HH - 1);
        int cx0 = gxc - GX0 + 3;                      // origin in labB (o=GX0-6, +6-3)
        int cy0 = gyc - GY0 + 3;
        ull rows[7];
        gather7<48>(labB, cx0, cy0, rows);
        labC[j * 40 + i] = (unsigned char)do_vote(rows, gxc, gyc, t, bins);
    }
    __syncthreads();

    // v5 for the 32x8 tile, one pixel per thread -> int32
    {
        const int x = GX0 + tx, y = GY0 + ty;
        ull rows[7];
        gather7<40>(labC, tx, ty, rows);
        out32[(b * HH + y) * WW + x] = do_vote(rows, x, y, t, bins);
    }
}

// ---------------------------------------------------------------------------
extern "C" void kernel_launch(void* const* d_in, const int* in_sizes, int n_in,
                              void* d_out, int out_size, void* d_ws, size_t ws_size,
                              hipStream_t stream) {
    (void)in_sizes; (void)n_in; (void)out_size; (void)ws_size;
    const float* grad = (const float*)d_in[0];
    int* out = (int*)d_out;
    char* ws = (char*)d_ws;

    int* cv = (int*)(ws);                               // 25088 B
    int* ch = (int*)(ws + 25088);                       // 25088 B
    unsigned char* laW = (unsigned char*)(ws + 50176);  // v2 label image (200704 B)

    dp_kernel<<<56, 64, 0, stream>>>(grad, cv, ch);

    dim3 grid(WW / 32, HH / 8, BB), blk(32, 8, 1);
    labvote2_kernel<<<grid, blk, 0, stream>>>(cv, ch, laW);   // labels + v1 + v2 -> laW
    vote3_kernel<<<grid, blk, 0, stream>>>(laW, out);         // v3 + v4 + v5 -> int out
}

// Round 6
// 112.555 us; speedup vs baseline: 1.3182x; 1.3182x over previous
//
#include <hip/hip_runtime.h>
#include <stdint.h>

#define HH 224
#define WW 224
#define BB 4
#define PP 7          // seams per direction
#define SEG 28
#define BW 5
#define MM 11         // 2*BW+1

#define POS_INF_I 0x7F800000

typedef const __attribute__((address_space(1))) unsigned int* gas_ptr;
typedef __attribute__((address_space(3))) unsigned int* las_ptr;
typedef unsigned long long ull;

// map-compose for 11-entry 4-bit-nibble maps packed in u64:  H[i] = F[G[i]]
__device__ inline ull mcompose(ull F, ull G) {
    ull H = 0ull;
#pragma unroll
    for (int i = 0; i < 11; ++i) {
        unsigned g = (unsigned)(G >> (4 * i)) & 15u;
        H |= ((F >> (4 * g)) & 15ull) << (4 * i);
    }
    return H;
}

// ---------------------------------------------------------------------------
// XCD-consistent tile map (T1 / m157 recipe). Flat grid of 784 blocks.
// Physical block p (assumed XCD = p%8 round-robin) gets virtual tile
// v = (p%8)*98 + p/8, so each XCD owns a contiguous {batch, 14-tile-row}
// band ACROSS ALL STENCIL DISPATCHES -> a tile's self + most of its halo
// was written by same-XCD blocks in the previous dispatch (local L2 hits).
// Pure bijection: correctness independent of the actual XCD mapping.
// ---------------------------------------------------------------------------
__device__ __forceinline__ void tile_map(int& bx, int& by, int& b) {
    int p = blockIdx.x;
    int v = (p & 7) * 98 + (p >> 3);
    bx = v % 7;
    int r = v / 7;
    by = r % 28;
    b  = r / 28;
}

// ---------------------------------------------------------------------------
// DP kernel (verified absmax 0 — unchanged from round 0)
// ---------------------------------------------------------------------------
__global__ __launch_bounds__(64) void dp_kernel(const float* __restrict__ grad,
                                                int* __restrict__ coords_v,
                                                int* __restrict__ coords_h) {
    __shared__ __align__(16) float gseg[225 * 16];

    const int tid = threadIdx.x;
    const int l   = tid & 15;
    const int sid = blockIdx.x;
    const int p   = sid % PP;
    const int dir = (sid / PP) & 1;
    const int b   = sid / (2 * PP);
    const int base = SEG * (p + 1);
    const float* gb = grad + b * (HH * WW);

    {
        const int r  = tid >> 4;
        const int m  = tid & 15;
        const int sS = (dir == 0) ? WW : 1;
        const int sM = (dir == 0) ? 1  : WW;
        const float* src = gb + r * sS + (base - BW + m) * sM;
        const long stepBytes = (long)(4 * sS) * 4;
#pragma unroll 8
        for (int c = 0; c < 56; ++c) {
            __builtin_amdgcn_global_load_lds((gas_ptr)(const void*)src,
                                             (las_ptr)(void*)(&gseg[c * 64]), 4, 0, 0);
            src = (const float*)((const char*)src + stepBytes);
        }
    }
    __syncthreads();

    const float lane_add = (l < MM) ? 0.0f : __int_as_float(POS_INF_I);
    const float* gp = &gseg[l];

    unsigned wreg[16] = {};

#define DP_STEP(gval, ownb, jj_c)                                                       \
    {                                                                                   \
        float v1 = cost;                                                                \
        float v0 = __int_as_float(__builtin_amdgcn_update_dpp(                          \
            POS_INF_I, __float_as_int(cost), 0x111, 0xf, 0xf, false));                  \
        float v2 = __int_as_float(__builtin_amdgcn_update_dpp(                          \
            POS_INF_I, __float_as_int(cost), 0x101, 0xf, 0xf, false));                  \
        bool a01 = (v0 <= v1), a02 = (v0 <= v2), a12 = (v1 <= v2);                      \
        bool aa  = a01 && a02;                                                          \
        unsigned long long A   = __ballot(aa);                                          \
        unsigned long long C12 = __ballot(a12);                                         \
        unsigned long long B0 = ~A & C12;                                               \
        unsigned long long B1 = ~A & ~C12;                                              \
        float mv = aa ? v0 : (a12 ? v1 : v2);                                           \
        cost = mv - (gval) + lane_add;                                                  \
        unsigned wv = (unsigned)(B0 & 0x7FFull) | ((unsigned)(B1 & 0x7FFull) << 11);    \
        wreg[(jj_c)] = (ownb) ? wv : wreg[(jj_c)];                                      \
    }

    float cost = -gp[0] + lane_add;
    float buf[16], c0[16];
#pragma unroll
    for (int k = 0; k < 16; ++k) buf[k] = gp[(1 + k) * 16];
    for (int t = 0; t < 13; ++t) {
        const bool own = (tid == t);
#pragma unroll
        for (int k = 0; k < 16; ++k) c0[k] = buf[k];
#pragma unroll
        for (int k = 0; k < 16; ++k) buf[k] = gp[(16 * (t + 1) + 1 + k) * 16];
#pragma unroll
        for (int k = 0; k < 16; ++k) DP_STEP(c0[k], own, k)
    }
    {
        const bool own = (tid == 13);
#pragma unroll
        for (int k = 0; k < 15; ++k) DP_STEP(buf[k], own, k)
    }
#undef DP_STEP

    float bc = cost;
    int   bi = l;
#pragma unroll
    for (int mask = 1; mask < 16; mask <<= 1) {
        float oc = __shfl_xor(bc, mask, 16);
        int   oi = __shfl_xor(bi, mask, 16);
        if (oc < bc || (oc == bc && oi < bi)) { bc = oc; bi = oi; }
    }
    const int idx_last = bi;

    const int mcnt = (l < 13) ? 16 : ((l == 13) ? 15 : 0);
    const ull IDMAP = 0xA9876543210ull;
    ull L = IDMAP;
#pragma unroll
    for (int jj = 15; jj >= 0; --jj) {
        if (jj < mcnt) {
            unsigned ww = wreg[jj];
            ull M = 0ull;
#pragma unroll
            for (int i = 0; i < MM; ++i) {
                unsigned sel = ((ww >> i) & 1u) + 2u * ((ww >> (11 + i)) & 1u);
                M |= ((ull)(i + (int)sel - 1)) << (4 * i);
            }
            L = mcompose(M, L);
        }
    }
    ull I = L;
#pragma unroll
    for (int d = 1; d < 16; d <<= 1) {
        ull O = __shfl_down(I, d, 16);
        if (l + d < 16) I = mcompose(I, O);
    }
    ull R = __shfl_down(I, 1, 16);
    if (l == 15) R = IDMAP;

    int* cout = (dir == 0) ? coords_v : coords_h;
    if (tid == 15) cout[(b * HH + 223) * PP + p] = base + idx_last - BW;
    if (tid < 16) {
        unsigned v = (unsigned)(R >> (4 * idx_last)) & 15u;
#pragma unroll
        for (int jj = 15; jj >= 0; --jj) {
            if (jj < mcnt) {
                unsigned ww = wreg[jj];
                unsigned sel = ((ww >> v) & 1u) + 2u * ((ww >> (11 + v)) & 1u);
                v = v + sel - 1u;
                cout[(b * HH + (16 * l + jj)) * PP + p] = base + (int)v - BW;
            }
        }
    }
}

// ---------------------------------------------------------------------------
// labvote: initial labels (analytic, 38x14 LDS region) + vote iteration 1.
// Round-0 proven body; only the tile decode changed to the XCD map.
// Flat grid 784 x 256 threads.
// ---------------------------------------------------------------------------
#define RW 38
#define RH 14
#define RSTR 40

__global__ __launch_bounds__(256) void labvote_kernel(const int* __restrict__ cv,
                                                      const int* __restrict__ ch,
                                                      unsigned char* __restrict__ out8) {
    __shared__ unsigned char lab[RH * RSTR];
    __shared__ unsigned bins[16 * 256];
    const int tx = threadIdx.x & 31, ty = threadIdx.x >> 5;
    const int t  = threadIdx.x;
    int bxt, byt, b;
    tile_map(bxt, byt, b);
    const int GX0 = bxt * 32, GY0 = byt * 8;

    for (int idx = t; idx < RW * RH; idx += 256) {
        int j = idx / RW, i = idx - j * RW;
        int gx = GX0 - 3 + i, gy = GY0 - 3 + j;
        if ((unsigned)gx < WW && (unsigned)gy < HH) {
            const int* cvp = cv + (b * HH + gy) * PP;
            const int* chp = ch + (b * WW + gx) * PP;
            int v = 0, h = 0;
#pragma unroll
            for (int q = 0; q < PP; ++q) { v += (cvp[q] <= gx); h += (chp[q] <= gy); }
            lab[j * RSTR + i] = (unsigned char)(v + 8 * h);
        }
    }
    __syncthreads();

    const int gx = GX0 + tx, gy = GY0 + ty;
#pragma unroll
    for (int c = 0; c < 16; ++c) bins[c * 256 + t] = 0u;
#pragma unroll
    for (int dy = -3; dy <= 3; ++dy) {
        if ((unsigned)(gy + dy) >= HH) continue;
#pragma unroll
        for (int dx = -3; dx <= 3; ++dx) {
            if ((unsigned)(gx + dx) >= WW) continue;
            int lb = lab[(ty + 3 + dy) * RSTR + (tx + 3 + dx)];
            int ay = dy < 0 ? -dy : dy, ax = dx < 0 ? -dx : dx;
            int d = ay > ax ? ay : ax;
            unsigned wgt = (d <= 1) ? 3u : (unsigned)(4 - d);
            atomicAdd(&bins[(lb >> 2) * 256 + t], wgt << ((lb & 3) * 8));
        }
    }
    int best_s = 0, best_k = 0;
#pragma unroll
    for (int c = 0; c < 16; ++c) {
        unsigned wd = bins[c * 256 + t];
        if (wd) {
#pragma unroll
            for (int q = 0; q < 4; ++q) {
                int s = (int)((wd >> (q * 8)) & 255u);
                if (s > best_s) { best_s = s; best_k = c * 4 + q; }
            }
        }
    }
    out8[(b * HH + gy) * WW + gx] = (unsigned char)best_k;
}

// ---------------------------------------------------------------------------
// vote: round-0 proven body (packed dword gather, uniform fast path, bins
// slow path); only the tile decode changed to the XCD map. Flat grid 784.
// ---------------------------------------------------------------------------
__global__ __launch_bounds__(256) void vote_kernel(const unsigned char* __restrict__ in,
                                                   unsigned char* __restrict__ out8,
                                                   int* __restrict__ out32) {
    __shared__ unsigned bins[16 * 256];
    const int tx = threadIdx.x & 31, ty = threadIdx.x >> 5;
    const int t  = threadIdx.x;
    int bxt, byt, b;
    tile_map(bxt, byt, b);
    const int x = bxt * 32 + tx;
    const int y = byt * 8 + ty;
    const unsigned char* img = in + b * (HH * WW);

    ull rows[7];
    const bool xedge = (bxt == 0) || (bxt == (WW / 32 - 1));
    if (!xedge) {
        // interior-x: bytes x-3..x+3 are in-image; 3 aligned dword loads/row
        const unsigned* img32 = (const unsigned*)img;
        const int o0 = x - 3;
#pragma unroll
        for (int dy = -3; dy <= 3; ++dy) {
            int yc = min(max(y + dy, 0), HH - 1);
            int o  = yc * WW + o0;
            int a  = o >> 2;
            int sh = (o & 3) * 8;
            unsigned d0 = img32[a], d1 = img32[a + 1], d2 = img32[a + 2];
            ull lo = ((ull)d1 << 32) | d0;
            ull row = lo >> sh;
            if (sh) row |= (ull)d2 << (64 - sh);
            rows[dy + 3] = row & 0x00FFFFFFFFFFFFFFull;
        }
    } else {
        // x-edge blocks: per-byte clamped gather (proven addressing)
#pragma unroll
        for (int dy = -3; dy <= 3; ++dy) {
            int yc = min(max(y + dy, 0), HH - 1);
            ull row = 0ull;
#pragma unroll
            for (int dx = -3; dx <= 3; ++dx) {
                int xc = min(max(x + dx, 0), WW - 1);
                row |= (ull)img[yc * WW + xc] << (8 * (dx + 3));
            }
            rows[dy + 3] = row;
        }
    }

    const unsigned labc = (unsigned)((rows[3] >> 24) & 255u);   // dy=0, dx=0
    const ull rep = (ull)labc * 0x0001010101010101ull;          // 7 bytes replicated
    bool uni = true;
#pragma unroll
    for (int k = 0; k < 7; ++k) uni = uni && (rows[k] == rep);

    int best_k;
    if (uni) {
        // all clamped-window bytes == center  =>  every valid neighbor == center
        // => center is the unique positive vote => argmax = center. Exact.
        best_k = (int)labc;
    } else {
#pragma unroll
        for (int c = 0; c < 16; ++c) bins[c * 256 + t] = 0u;
#pragma unroll
        for (int dy = -3; dy <= 3; ++dy) {
            if ((unsigned)(y + dy) >= (unsigned)HH) continue;
            ull row = rows[dy + 3];
            const int ay = dy < 0 ? -dy : dy;
#pragma unroll
            for (int dx = -3; dx <= 3; ++dx) {
                if ((unsigned)(x + dx) >= (unsigned)WW) continue;
                int lb = (int)((row >> (8 * (dx + 3))) & 255u);
                const int ax = dx < 0 ? -dx : dx;
                const int d = ay > ax ? ay : ax;
                const unsigned wgt = (d <= 1) ? 3u : (unsigned)(4 - d);
                atomicAdd(&bins[(lb >> 2) * 256 + t], wgt << ((lb & 3) * 8));
            }
        }
        int best_s = 0; best_k = 0;
#pragma unroll
        for (int c = 0; c < 16; ++c) {
            unsigned wd = bins[c * 256 + t];
            if (wd) {
#pragma unroll
                for (int q = 0; q < 4; ++q) {
                    int s = (int)((wd >> (q * 8)) & 255u);
                    if (s > best_s) { best_s = s; best_k = c * 4 + q; }
                }
            }
        }
    }

    int o = (b * HH + y) * WW + x;
    if (out8)  out8[o]  = (unsigned char)best_k;
    if (out32) out32[o] = best_k;
}

// ---------------------------------------------------------------------------
extern "C" void kernel_launch(void* const* d_in, const int* in_sizes, int n_in,
                              void* d_out, int out_size, void* d_ws, size_t ws_size,
                              hipStream_t stream) {
    (void)in_sizes; (void)n_in; (void)out_size; (void)ws_size;
    const float* grad = (const float*)d_in[0];
    int* out = (int*)d_out;
    char* ws = (char*)d_ws;

    int* cv = (int*)(ws);                               // 25088 B
    int* ch = (int*)(ws + 25088);                       // 25088 B
    unsigned char* laW = (unsigned char*)(ws + 50176);  // ping (ws)
    unsigned char* laD = (unsigned char*)d_out;         // pong (inside d_out)

    dp_kernel<<<56, 64, 0, stream>>>(grad, cv, ch);

    dim3 grid(784, 1, 1), blk(256, 1, 1);               // flat; XCD map in-kernel
    labvote_kernel<<<grid, blk, 0, stream>>>(cv, ch, laD);        // v1 -> laD
    vote_kernel<<<grid, blk, 0, stream>>>(laD, laW, nullptr);     // v2 -> laW
    vote_kernel<<<grid, blk, 0, stream>>>(laW, laD, nullptr);     // v3 -> laD
    vote_kernel<<<grid, blk, 0, stream>>>(laD, laW, nullptr);     // v4 -> laW
    vote_kernel<<<grid, blk, 0, stream>>>(laW, nullptr, out);     // v5 -> int out
}

// Round 8
// 111.647 us; speedup vs baseline: 1.3289x; 1.0081x over previous
//
#include <hip/hip_runtime.h>
#include <stdint.h>

#define HH 224
#define WW 224
#define BB 4
#define PP 7          // seams per direction
#define SEG 28
#define BW 5
#define MM 11         // 2*BW+1

#define POS_INF_I 0x7F800000

typedef const __attribute__((address_space(1))) unsigned int* gas_ptr;
typedef __attribute__((address_space(3))) unsigned int* las_ptr;
typedef unsigned long long ull;

// map-compose for 11-entry 4-bit-nibble maps packed in u64:  H[i] = F[G[i]]
__device__ inline ull mcompose(ull F, ull G) {
    ull H = 0ull;
#pragma unroll
    for (int i = 0; i < 11; ++i) {
        unsigned g = (unsigned)(G >> (4 * i)) & 15u;
        H |= ((F >> (4 * g)) & 15ull) << (4 * i);
    }
    return H;
}

// ---------------------------------------------------------------------------
// XCD-consistent tile map (proven +7us in round 6). Flat grid of 784 blocks
// decoding 16x16 tiles: 14x14 tiles per image x 4 batches.
// v = (p&7)*98 + p>>3 : each XCD owns 98 consecutive tiles (7 tile-rows of
// one image) -> halo neighbors land on the same XCD across dispatches.
// 784 = 8*98 exactly -> bijective.
// Decode check (round-7 bug fix): v = b*196 + by*14 + bx with
//   bx = v % 14, by = (v/14) % 14, b = v / 196.  (was: b = (v/14)/196 == 0)
// ---------------------------------------------------------------------------
__device__ __forceinline__ void tile_map(int& bx, int& by, int& b) {
    int p = blockIdx.x;
    int v = (p & 7) * 98 + (p >> 3);
    bx = v % 14;
    int r = v / 14;         // r = b*14 + by, range 0..55
    by = r % 14;
    b  = r / 14;            // FIXED (round 7 had r/196 -> always 0)
}

// square 8x8 wave quadrants inside the 16x16 tile: minimizes the fraction of
// waves whose exec mask contains a label-boundary pixel (slow-path trigger).
__device__ __forceinline__ void lane_map(int t, int& tx, int& ty) {
    const int lane = t & 63;
    const int w    = t >> 6;
    tx = ((w & 1) << 3) + (lane & 7);
    ty = ((w >> 1) << 3) + (lane >> 3);
}

// ---------------------------------------------------------------------------
// DP kernel (verified absmax 0 — unchanged)
// ---------------------------------------------------------------------------
__global__ __launch_bounds__(64) void dp_kernel(const float* __restrict__ grad,
                                                int* __restrict__ coords_v,
                                                int* __restrict__ coords_h) {
    __shared__ __align__(16) float gseg[225 * 16];

    const int tid = threadIdx.x;
    const int l   = tid & 15;
    const int sid = blockIdx.x;
    const int p   = sid % PP;
    const int dir = (sid / PP) & 1;
    const int b   = sid / (2 * PP);
    const int base = SEG * (p + 1);
    const float* gb = grad + b * (HH * WW);

    {
        const int r  = tid >> 4;
        const int m  = tid & 15;
        const int sS = (dir == 0) ? WW : 1;
        const int sM = (dir == 0) ? 1  : WW;
        const float* src = gb + r * sS + (base - BW + m) * sM;
        const long stepBytes = (long)(4 * sS) * 4;
#pragma unroll 8
        for (int c = 0; c < 56; ++c) {
            __builtin_amdgcn_global_load_lds((gas_ptr)(const void*)src,
                                             (las_ptr)(void*)(&gseg[c * 64]), 4, 0, 0);
            src = (const float*)((const char*)src + stepBytes);
        }
    }
    __syncthreads();

    const float lane_add = (l < MM) ? 0.0f : __int_as_float(POS_INF_I);
    const float* gp = &gseg[l];

    unsigned wreg[16] = {};

#define DP_STEP(gval, ownb, jj_c)                                                       \
    {                                                                                   \
        float v1 = cost;                                                                \
        float v0 = __int_as_float(__builtin_amdgcn_update_dpp(                          \
            POS_INF_I, __float_as_int(cost), 0x111, 0xf, 0xf, false));                  \
        float v2 = __int_as_float(__builtin_amdgcn_update_dpp(                          \
            POS_INF_I, __float_as_int(cost), 0x101, 0xf, 0xf, false));                  \
        bool a01 = (v0 <= v1), a02 = (v0 <= v2), a12 = (v1 <= v2);                      \
        bool aa  = a01 && a02;                                                          \
        unsigned long long A   = __ballot(aa);                                          \
        unsigned long long C12 = __ballot(a12);                                         \
        unsigned long long B0 = ~A & C12;                                               \
        unsigned long long B1 = ~A & ~C12;                                              \
        float mv = aa ? v0 : (a12 ? v1 : v2);                                           \
        cost = mv - (gval) + lane_add;                                                  \
        unsigned wv = (unsigned)(B0 & 0x7FFull) | ((unsigned)(B1 & 0x7FFull) << 11);    \
        wreg[(jj_c)] = (ownb) ? wv : wreg[(jj_c)];                                      \
    }

    float cost = -gp[0] + lane_add;
    float buf[16], c0[16];
#pragma unroll
    for (int k = 0; k < 16; ++k) buf[k] = gp[(1 + k) * 16];
    for (int t = 0; t < 13; ++t) {
        const bool own = (tid == t);
#pragma unroll
        for (int k = 0; k < 16; ++k) c0[k] = buf[k];
#pragma unroll
        for (int k = 0; k < 16; ++k) buf[k] = gp[(16 * (t + 1) + 1 + k) * 16];
#pragma unroll
        for (int k = 0; k < 16; ++k) DP_STEP(c0[k], own, k)
    }
    {
        const bool own = (tid == 13);
#pragma unroll
        for (int k = 0; k < 15; ++k) DP_STEP(buf[k], own, k)
    }
#undef DP_STEP

    float bc = cost;
    int   bi = l;
#pragma unroll
    for (int mask = 1; mask < 16; mask <<= 1) {
        float oc = __shfl_xor(bc, mask, 16);
        int   oi = __shfl_xor(bi, mask, 16);
        if (oc < bc || (oc == bc && oi < bi)) { bc = oc; bi = oi; }
    }
    const int idx_last = bi;

    const int mcnt = (l < 13) ? 16 : ((l == 13) ? 15 : 0);
    const ull IDMAP = 0xA9876543210ull;
    ull L = IDMAP;
#pragma unroll
    for (int jj = 15; jj >= 0; --jj) {
        if (jj < mcnt) {
            unsigned ww = wreg[jj];
            ull M = 0ull;
#pragma unroll
            for (int i = 0; i < MM; ++i) {
                unsigned sel = ((ww >> i) & 1u) + 2u * ((ww >> (11 + i)) & 1u);
                M |= ((ull)(i + (int)sel - 1)) << (4 * i);
            }
            L = mcompose(M, L);
        }
    }
    ull I = L;
#pragma unroll
    for (int d = 1; d < 16; d <<= 1) {
        ull O = __shfl_down(I, d, 16);
        if (l + d < 16) I = mcompose(I, O);
    }
    ull R = __shfl_down(I, 1, 16);
    if (l == 15) R = IDMAP;

    int* cout = (dir == 0) ? coords_v : coords_h;
    if (tid == 15) cout[(b * HH + 223) * PP + p] = base + idx_last - BW;
    if (tid < 16) {
        unsigned v = (unsigned)(R >> (4 * idx_last)) & 15u;
#pragma unroll
        for (int jj = 15; jj >= 0; --jj) {
            if (jj < mcnt) {
                unsigned ww = wreg[jj];
                unsigned sel = ((ww >> v) & 1u) + 2u * ((ww >> (11 + v)) & 1u);
                v = v + sel - 1u;
                cout[(b * HH + (16 * l + jj)) * PP + p] = base + (int)v - BW;
            }
        }
    }
}

// ---------------------------------------------------------------------------
// labvote: initial labels (analytic, 22x22 LDS region for the 16x16 tile) +
// vote iteration 1. Proven round-0 body; only region size and the square-wave
// lane map changed. Flat grid 784 x 256 threads.
// ---------------------------------------------------------------------------
#define RW 22
#define RH 22
#define RSTR 24

__global__ __launch_bounds__(256) void labvote_kernel(const int* __restrict__ cv,
                                                      const int* __restrict__ ch,
                                                      unsigned char* __restrict__ out8) {
    __shared__ unsigned char lab[RH * RSTR];
    __shared__ unsigned bins[16 * 256];
    const int t = threadIdx.x;
    int tx, ty;
    lane_map(t, tx, ty);
    int bxt, byt, b;
    tile_map(bxt, byt, b);
    const int GX0 = bxt * 16, GY0 = byt * 16;

    for (int idx = t; idx < RW * RH; idx += 256) {
        int j = idx / RW, i = idx - j * RW;
        int gx = GX0 - 3 + i, gy = GY0 - 3 + j;
        if ((unsigned)gx < WW && (unsigned)gy < HH) {
            const int* cvp = cv + (b * HH + gy) * PP;
            const int* chp = ch + (b * WW + gx) * PP;
            int v = 0, h = 0;
#pragma unroll
            for (int q = 0; q < PP; ++q) { v += (cvp[q] <= gx); h += (chp[q] <= gy); }
            lab[j * RSTR + i] = (unsigned char)(v + 8 * h);
        }
    }
    __syncthreads();

    const int gx = GX0 + tx, gy = GY0 + ty;
#pragma unroll
    for (int c = 0; c < 16; ++c) bins[c * 256 + t] = 0u;
#pragma unroll
    for (int dy = -3; dy <= 3; ++dy) {
        if ((unsigned)(gy + dy) >= HH) continue;
#pragma unroll
        for (int dx = -3; dx <= 3; ++dx) {
            if ((unsigned)(gx + dx) >= WW) continue;
            int lb = lab[(ty + 3 + dy) * RSTR + (tx + 3 + dx)];
            int ay = dy < 0 ? -dy : dy, ax = dx < 0 ? -dx : dx;
            int d = ay > ax ? ay : ax;
            unsigned wgt = (d <= 1) ? 3u : (unsigned)(4 - d);
            atomicAdd(&bins[(lb >> 2) * 256 + t], wgt << ((lb & 3) * 8));
        }
    }
    int best_s = 0, best_k = 0;
#pragma unroll
    for (int c = 0; c < 16; ++c) {
        unsigned wd = bins[c * 256 + t];
        if (wd) {
#pragma unroll
            for (int q = 0; q < 4; ++q) {
                int s = (int)((wd >> (q * 8)) & 255u);
                if (s > best_s) { best_s = s; best_k = c * 4 + q; }
            }
        }
    }
    out8[(b * HH + gy) * WW + gx] = (unsigned char)best_k;
}

// ---------------------------------------------------------------------------
// vote: proven round-0 body (packed dword gather, uniform fast path, bins
// slow path). 16x16 tiles, square 8x8 wave quadrants. Flat grid 784.
// ---------------------------------------------------------------------------
__global__ __launch_bounds__(256) void vote_kernel(const unsigned char* __restrict__ in,
                                                   unsigned char* __restrict__ out8,
                                                   int* __restrict__ out32) {
    __shared__ unsigned bins[16 * 256];
    const int t = threadIdx.x;
    int tx, ty;
    lane_map(t, tx, ty);
    int bxt, byt, b;
    tile_map(bxt, byt, b);
    const int x = bxt * 16 + tx;
    const int y = byt * 16 + ty;
    const unsigned char* img = in + b * (HH * WW);

    ull rows[7];
    const bool xedge = (bxt == 0) || (bxt == 13);
    if (!xedge) {
        // interior-x: bytes x-3..x+3 are in-image; 3 aligned dword loads/row
        const unsigned* img32 = (const unsigned*)img;
        const int o0 = x - 3;
#pragma unroll
        for (int dy = -3; dy <= 3; ++dy) {
            int yc = min(max(y + dy, 0), HH - 1);
            int o  = yc * WW + o0;
            int a  = o >> 2;
            int sh = (o & 3) * 8;
            unsigned d0 = img32[a], d1 = img32[a + 1], d2 = img32[a + 2];
            ull lo = ((ull)d1 << 32) | d0;
            ull row = lo >> sh;
            if (sh) row |= (ull)d2 << (64 - sh);
            rows[dy + 3] = row & 0x00FFFFFFFFFFFFFFull;
        }
    } else {
        // x-edge tiles: per-byte clamped gather (proven addressing)
#pragma unroll
        for (int dy = -3; dy <= 3; ++dy) {
            int yc = min(max(y + dy, 0), HH - 1);
            ull row = 0ull;
#pragma unroll
            for (int dx = -3; dx <= 3; ++dx) {
                int xc = min(max(x + dx, 0), WW - 1);
                row |= (ull)img[yc * WW + xc] << (8 * (dx + 3));
            }
            rows[dy + 3] = row;
        }
    }

    const unsigned labc = (unsigned)((rows[3] >> 24) & 255u);   // dy=0, dx=0
    const ull rep = (ull)labc * 0x0001010101010101ull;          // 7 bytes replicated
    bool uni = true;
#pragma unroll
    for (int k = 0; k < 7; ++k) uni = uni && (rows[k] == rep);

    int best_k;
    if (uni) {
        // all clamped-window bytes == center  =>  every valid neighbor == center
        // => center is the unique positive vote => argmax = center. Exact.
        best_k = (int)labc;
    } else {
#pragma unroll
        for (int c = 0; c < 16; ++c) bins[c * 256 + t] = 0u;
#pragma unroll
        for (int dy = -3; dy <= 3; ++dy) {
            if ((unsigned)(y + dy) >= (unsigned)HH) continue;
            ull row = rows[dy + 3];
            const int ay = dy < 0 ? -dy : dy;
#pragma unroll
            for (int dx = -3; dx <= 3; ++dx) {
                if ((unsigned)(x + dx) >= (unsigned)WW) continue;
                int lb = (int)((row >> (8 * (dx + 3))) & 255u);
                const int ax = dx < 0 ? -dx : dx;
                const int d = ay > ax ? ay : ax;
                const unsigned wgt = (d <= 1) ? 3u : (unsigned)(4 - d);
                atomicAdd(&bins[(lb >> 2) * 256 + t], wgt << ((lb & 3) * 8));
            }
        }
        int best_s = 0; best_k = 0;
#pragma unroll
        for (int c = 0; c < 16; ++c) {
            unsigned wd = bins[c * 256 + t];
            if (wd) {
#pragma unroll
                for (int q = 0; q < 4; ++q) {
                    int s = (int)((wd >> (q * 8)) & 255u);
                    if (s > best_s) { best_s = s; best_k = c * 4 + q; }
                }
            }
        }
    }

    int o = (b * HH + y) * WW + x;
    if (out8)  out8[o]  = (unsigned char)best_k;
    if (out32) out32[o] = best_k;
}

// ---------------------------------------------------------------------------
extern "C" void kernel_launch(void* const* d_in, const int* in_sizes, int n_in,
                              void* d_out, int out_size, void* d_ws, size_t ws_size,
                              hipStream_t stream) {
    (void)in_sizes; (void)n_in; (void)out_size; (void)ws_size;
    const float* grad = (const float*)d_in[0];
    int* out = (int*)d_out;
    char* ws = (char*)d_ws;

    int* cv = (int*)(ws);                               // 25088 B
    int* ch = (int*)(ws + 25088);                       // 25088 B
    unsigned char* laW = (unsigned char*)(ws + 50176);  // ping (ws)
    unsigned char* laD = (unsigned char*)d_out;         // pong (inside d_out)

    dp_kernel<<<56, 64, 0, stream>>>(grad, cv, ch);

    dim3 grid(784, 1, 1), blk(256, 1, 1);               // flat; XCD map in-kernel
    labvote_kernel<<<grid, blk, 0, stream>>>(cv, ch, laD);        // v1 -> laD
    vote_kernel<<<grid, blk, 0, stream>>>(laD, laW, nullptr);     // v2 -> laW
    vote_kernel<<<grid, blk, 0, stream>>>(laW, laD, nullptr);     // v3 -> laD
    vote_kernel<<<grid, blk, 0, stream>>>(laD, laW, nullptr);     // v4 -> laW
    vote_kernel<<<grid, blk, 0, stream>>>(laW, nullptr, out);     // v5 -> int out
}